// Round 4
// baseline (873.874 us; speedup 1.0000x reference)
//
#include <hip/hip_runtime.h>

#define Bn 4
#define Nn 50000
#define En 1000000
#define FOUT 8
#define HID 64

typedef unsigned int u32;
typedef unsigned short u16;
typedef __attribute__((ext_vector_type(8))) short bf16x8;
typedef __attribute__((ext_vector_type(4))) float f32x4;
typedef __attribute__((ext_vector_type(4))) int i32x4;

// ws layout: [weight blob 24576 B][ksum Bn*Nn*8 f32][deg Nn f32]
#define BLOB_BYTES 24576
#define W1T_OFF 0
#define W2T_OFF 4096
#define W3T_OFF 12288
#define B1_OFF 20480
#define B2_OFF 20736
#define B3_OFF 20992
#define BLOB_USED 21248   // 1328 * 16

__device__ __forceinline__ float fast_tanh(float x) {
    // tanh(x) = 1 - 2/(e^{2x}+1); saturates correctly at +/-inf via exp2/rcp.
    float e = __builtin_amdgcn_exp2f(x * 2.8853900817779268f);
    return 1.0f - 2.0f * __builtin_amdgcn_rcpf(e + 1.0f);
}
__device__ __forceinline__ u32 pkbf(float lo, float hi) {
    u32 r;
    asm("v_cvt_pk_bf16_f32 %0, %1, %2" : "=v"(r) : "v"(lo), "v"(hi));
    return r;
}
__device__ __forceinline__ float bflo(u32 u) { return __builtin_bit_cast(float, u << 16); }
__device__ __forceinline__ float bfhi(u32 u) { return __builtin_bit_cast(float, u & 0xffff0000u); }
__device__ __forceinline__ u16 f2bf(float x) {
    u32 u = __builtin_bit_cast(u32, x);
    return (u16)((u + 0x7fff + ((u >> 16) & 1)) >> 16);
}
// sigma: D-position q = 16*mi + 4*g + r  ->  actual output channel
// o = 32*(mi>>1) + 8*g + 4*(mi&1) + r   (bijective; makes lane-held == lane-needed
// for the next layer's B-fragment: slots {q=32kt+4g+j', q=32kt+16+4g+j'} map to
// channels 32kt+8g+{0..3, 4..7} exactly -- verified symbolically)
__device__ __forceinline__ int PERM(int q) {
    int mi = q >> 4, g = (q >> 2) & 3, r = q & 3;
    return ((mi >> 1) << 5) | (g << 3) | ((mi & 1) << 2) | r;
}

// ---- init: bf16-convert, transpose, sigma-permute, XOR-swizzle weights into ws blob ----
// 64B-row regions (W1T) use full-address XOR  addr ^= ((row&7)<<4)  (bijective across
// each 128B row-pair; spreads 8 rows over all 8 16B slots -> ds_read_b128 bank floor).
// 128B-row regions (W2T/W3T) use within-row XOR ((row&7)<<4), same effect.
__global__ void gno_init_weights(const float* __restrict__ W1, const float* __restrict__ b1,
                                 const float* __restrict__ W2, const float* __restrict__ b2,
                                 const float* __restrict__ W3, const float* __restrict__ b3,
                                 unsigned char* __restrict__ blob)
{
    int idx = blockIdx.x * 256 + threadIdx.x;
    if (idx < 2048) {                       // W1T_s[q][k], k padded 20->32, rows 64B
        int q = idx >> 5, k = idx & 31;
        float v = (k < 20) ? W1[k * 64 + PERM(q)] : 0.0f;
        *(u16*)(blob + W1T_OFF + ((q * 64 + 2 * k) ^ ((q & 7) << 4))) = f2bf(v);
    } else if (idx < 6144) {                // W2T_s[q][k], rows 128B
        int j = idx - 2048, q = j >> 6, k = j & 63;
        *(u16*)(blob + W2T_OFF + q * 128 + ((2 * k) ^ ((q & 7) << 4))) = f2bf(W2[k * 64 + PERM(q)]);
    } else if (idx < 10240) {               // W3T[c][k], natural c order (mats cols)
        int j = idx - 6144, c = j >> 6, k = j & 63;
        *(u16*)(blob + W3T_OFF + c * 128 + ((2 * k) ^ ((c & 7) << 4))) = f2bf(W3[k * 64 + c]);
    } else if (idx < 10304) { int q = idx - 10240; *(float*)(blob + B1_OFF + q * 4) = b1[PERM(q)]; }
    else if (idx < 10368)   { int q = idx - 10304; *(float*)(blob + B2_OFF + q * 4) = b2[PERM(q)]; }
    else if (idx < 10432)   { int c = idx - 10368; *(float*)(blob + B3_OFF + c * 4) = b3[c]; }
}

// ---- main: 64 edges x 4 batches per block; wave = batch; MFMA 16x16x32 bf16 ----
__global__ __launch_bounds__(256) void gno_edge_mfma(
    const float* __restrict__ batch, const float* __restrict__ points,
    const int* __restrict__ neigh, const unsigned char* __restrict__ wblob,
    float* __restrict__ ksum)
{
    __shared__ __align__(128) unsigned char wlds[BLOB_USED];
    __shared__ __align__(128) unsigned char feat_lds[4 * 64 * 64];  // [b][e][32 bf16], 64B rows
    __shared__ __align__(16) unsigned char by_lds[4 * 64 * 16];     // [b][e][8 bf16]
    __shared__ int dst_lds[64];

    const int tid = threadIdx.x;
    const int lane = tid & 63;
    const int b = tid >> 6;          // wave id == batch index
    const int t = lane & 15;
    const int g = lane >> 4;
    const int e0 = blockIdx.x * 64;

    // stage weights (linear copy; blob already in final swizzled byte order)
    for (int i = tid; i < BLOB_USED / 16; i += 256)
        *(uint4*)(wlds + i * 16) = *(const uint4*)(wblob + i * 16);

    // stage feat rows: each wave stages its own batch's 64 edges
    {
        const int e = lane;
        const int dn = neigh[e0 + e];
        const int sn = neigh[En + e0 + e];
        const float2 ps = *(const float2*)(points + 2 * (size_t)sn);
        const float2 pd = *(const float2*)(points + 2 * (size_t)dn);
        const float4* bxp = (const float4*)(batch + ((size_t)b * Nn + sn) * 8);
        const float4 bx0 = bxp[0], bx1 = bxp[1];
        const float4* byp = (const float4*)(batch + ((size_t)b * Nn + dn) * 8);
        const float4 by0 = byp[0], by1 = byp[1];
        unsigned char* fb = feat_lds + b * 4096;
        const int base = e << 6;
        const int sw = (e & 7) << 4;
        *(uint4*)(fb + ((base + 0)  ^ sw)) = make_uint4(pkbf(ps.x, ps.y), pkbf(pd.x, pd.y),
                                                        pkbf(bx0.x, bx0.y), pkbf(bx0.z, bx0.w));
        *(uint4*)(fb + ((base + 16) ^ sw)) = make_uint4(pkbf(bx1.x, bx1.y), pkbf(bx1.z, bx1.w),
                                                        pkbf(by0.x, by0.y), pkbf(by0.z, by0.w));
        *(uint4*)(fb + ((base + 32) ^ sw)) = make_uint4(pkbf(by1.x, by1.y), pkbf(by1.z, by1.w), 0u, 0u);
        *(uint4*)(fb + ((base + 48) ^ sw)) = make_uint4(0u, 0u, 0u, 0u);
        *(uint4*)(by_lds + b * 1024 + e * 16) = make_uint4(pkbf(by0.x, by0.y), pkbf(by0.z, by0.w),
                                                           pkbf(by1.x, by1.y), pkbf(by1.z, by1.w));
        if (b == 0) dst_lds[e] = dn;
    }
    __syncthreads();

    f32x4 acc[4][4], acc2[4][4];
    bf16x8 afr[4], bfr[4];
    u32 pk[4][4][2];

    // ----- L1: G1[q][e] = sum_k W1T_s[q][k] * feat[e][k] + b1s[q]  (K=32, one step) -----
    #pragma unroll
    for (int mi = 0; mi < 4; ++mi) {
        const f32x4 bv = *(const f32x4*)(wlds + B1_OFF + (mi * 16 + g * 4) * 4);
        #pragma unroll
        for (int ni = 0; ni < 4; ++ni) acc[mi][ni] = bv;
    }
    #pragma unroll
    for (int mi = 0; mi < 4; ++mi) {
        const int row = mi * 16 + t;
        afr[mi] = *(const bf16x8*)(wlds + W1T_OFF + ((row * 64 + (g << 4)) ^ ((row & 7) << 4)));
    }
    #pragma unroll
    for (int nj = 0; nj < 4; ++nj) {
        const int row = nj * 16 + t;
        bfr[nj] = *(const bf16x8*)(feat_lds + b * 4096 + ((row * 64 + (g << 4)) ^ ((row & 7) << 4)));
    }
    #pragma unroll
    for (int mi = 0; mi < 4; ++mi)
        #pragma unroll
        for (int nj = 0; nj < 4; ++nj)
            acc[mi][nj] = __builtin_amdgcn_mfma_f32_16x16x32_bf16(afr[mi], bfr[nj], acc[mi][nj], 0, 0, 0);

    // tanh + pack (in-register handoff; sigma makes lane-held == lane-needed)
    #pragma unroll
    for (int mi = 0; mi < 4; ++mi)
        #pragma unroll
        for (int ni = 0; ni < 4; ++ni) {
            pk[mi][ni][0] = pkbf(fast_tanh(acc[mi][ni][0]), fast_tanh(acc[mi][ni][1]));
            pk[mi][ni][1] = pkbf(fast_tanh(acc[mi][ni][2]), fast_tanh(acc[mi][ni][3]));
        }

    // ----- L2: K=64, 2 K-steps; B-frags straight from pk registers -----
    #pragma unroll
    for (int mi = 0; mi < 4; ++mi) {
        const f32x4 bv = *(const f32x4*)(wlds + B2_OFF + (mi * 16 + g * 4) * 4);
        #pragma unroll
        for (int ni = 0; ni < 4; ++ni) acc2[mi][ni] = bv;
    }
    #pragma unroll
    for (int kt = 0; kt < 2; ++kt) {
        #pragma unroll
        for (int mi = 0; mi < 4; ++mi) {
            const int row = mi * 16 + t;
            afr[mi] = *(const bf16x8*)(wlds + W2T_OFF + row * 128 +
                                       ((((kt << 2) + g) << 4) ^ ((row & 7) << 4)));
        }
        #pragma unroll
        for (int nj = 0; nj < 4; ++nj) {
            const i32x4 bi = { (int)pk[2 * kt][nj][0], (int)pk[2 * kt][nj][1],
                               (int)pk[2 * kt + 1][nj][0], (int)pk[2 * kt + 1][nj][1] };
            const bf16x8 bf = __builtin_bit_cast(bf16x8, bi);
            #pragma unroll
            for (int mi = 0; mi < 4; ++mi)
                acc2[mi][nj] = __builtin_amdgcn_mfma_f32_16x16x32_bf16(afr[mi], bf, acc2[mi][nj], 0, 0, 0);
        }
    }
    #pragma unroll
    for (int mi = 0; mi < 4; ++mi)
        #pragma unroll
        for (int ni = 0; ni < 4; ++ni) {
            pk[mi][ni][0] = pkbf(fast_tanh(acc2[mi][ni][0]), fast_tanh(acc2[mi][ni][1]));
            pk[mi][ni][1] = pkbf(fast_tanh(acc2[mi][ni][2]), fast_tanh(acc2[mi][ni][3]));
        }

    // ----- L3: mats cols natural (c = 16*mi + 4*g + r), + b3 -----
    #pragma unroll
    for (int mi = 0; mi < 4; ++mi) {
        const f32x4 bv = *(const f32x4*)(wlds + B3_OFF + (mi * 16 + g * 4) * 4);
        #pragma unroll
        for (int ni = 0; ni < 4; ++ni) acc[mi][ni] = bv;
    }
    #pragma unroll
    for (int kt = 0; kt < 2; ++kt) {
        #pragma unroll
        for (int mi = 0; mi < 4; ++mi) {
            const int row = mi * 16 + t;
            afr[mi] = *(const bf16x8*)(wlds + W3T_OFF + row * 128 +
                                       ((((kt << 2) + g) << 4) ^ ((row & 7) << 4)));
        }
        #pragma unroll
        for (int nj = 0; nj < 4; ++nj) {
            const i32x4 bi = { (int)pk[2 * kt][nj][0], (int)pk[2 * kt][nj][1],
                               (int)pk[2 * kt + 1][nj][0], (int)pk[2 * kt + 1][nj][1] };
            const bf16x8 bf = __builtin_bit_cast(bf16x8, bi);
            #pragma unroll
            for (int mi = 0; mi < 4; ++mi)
                acc[mi][nj] = __builtin_amdgcn_mfma_f32_16x16x32_bf16(afr[mi], bf, acc[mi][nj], 0, 0, 0);
        }
    }

    // ----- epilogue: c = 16mi+4g+r -> i = 2mi+(g>>1), j = (g&1)*4+r; pair-join over lane^16 -----
    const int i_hi = (lane >> 5) & 1;
    const int jhalf = g & 1;
    #pragma unroll
    for (int ni = 0; ni < 4; ++ni) {
        const int e = ni * 16 + t;
        const uint2 byw = *(const uint2*)(by_lds + b * 1024 + e * 16 + jhalf * 8);
        const float f0 = bflo(byw.x), f1 = bfhi(byw.x), f2 = bflo(byw.y), f3 = bfhi(byw.y);
        const int dn = dst_lds[e];
        float* kout = ksum + ((size_t)b * Nn + dn) * FOUT;
        #pragma unroll
        for (int mi = 0; mi < 4; ++mi) {
            const f32x4 a = acc[mi][ni];
            float p = fmaf(a[0], f0, fmaf(a[1], f1, fmaf(a[2], f2, a[3] * f3)));
            const float m = p + __shfl_xor(p, 16, 64);
            if (!(lane & 16)) unsafeAtomicAdd(kout + (2 * mi + i_hi), m);
        }
    }
}

__global__ void gno_deg_kernel(const int* __restrict__ neigh, float* __restrict__ deg) {
    const int e = blockIdx.x * 256 + threadIdx.x;
    if (e < En) unsafeAtomicAdd(&deg[neigh[e]], 1.0f);
}

__global__ void gno_out_kernel(const float* __restrict__ batch,
                               const float* __restrict__ Wlin,
                               const float* __restrict__ ksum,
                               const float* __restrict__ deg,
                               float* __restrict__ out)
{
    const int tt = blockIdx.x * 256 + threadIdx.x;
    if (tt >= Bn * Nn) return;
    const int n = tt % Nn;
    const float4* bp = (const float4*)(batch + (size_t)tt * 8);
    const float4 x0 = bp[0], x1 = bp[1];
    const float x[8] = {x0.x, x0.y, x0.z, x0.w, x1.x, x1.y, x1.z, x1.w};
    const float r = __builtin_amdgcn_rcpf(deg[n] + 1.0f);
    const float4* kp = (const float4*)(ksum + (size_t)tt * FOUT);
    const float4 k0 = kp[0], k1 = kp[1];
    const float ks[8] = {k0.x, k0.y, k0.z, k0.w, k1.x, k1.y, k1.z, k1.w};
    float o[8];
    #pragma unroll
    for (int i = 0; i < FOUT; ++i) {
        float v = ks[i] * r;
        #pragma unroll
        for (int j = 0; j < 8; ++j) v = fmaf(x[j], Wlin[j * FOUT + i], v);
        o[i] = v;
    }
    float4* op = (float4*)(out + (size_t)tt * FOUT);
    op[0] = make_float4(o[0], o[1], o[2], o[3]);
    op[1] = make_float4(o[4], o[5], o[6], o[7]);
}

extern "C" void kernel_launch(void* const* d_in, const int* in_sizes, int n_in,
                              void* d_out, int out_size, void* d_ws, size_t ws_size,
                              hipStream_t stream) {
    const float* batch  = (const float*)d_in[0];
    const float* points = (const float*)d_in[1];
    const int*   neigh  = (const int*)d_in[2];
    const float* W1     = (const float*)d_in[3];
    const float* b1     = (const float*)d_in[4];
    const float* W2     = (const float*)d_in[5];
    const float* b2     = (const float*)d_in[6];
    const float* W3     = (const float*)d_in[7];
    const float* b3     = (const float*)d_in[8];
    const float* Wlin   = (const float*)d_in[9];
    float* out = (float*)d_out;

    unsigned char* blob = (unsigned char*)d_ws;
    float* ksum = (float*)((unsigned char*)d_ws + BLOB_BYTES);
    float* deg  = ksum + (size_t)Bn * Nn * FOUT;
    const size_t ws_needed = BLOB_BYTES + ((size_t)Bn * Nn * FOUT + Nn) * sizeof(float);
    if (ws_size < ws_needed) return;

    hipMemsetAsync((unsigned char*)d_ws + BLOB_BYTES, 0,
                   ((size_t)Bn * Nn * FOUT + Nn) * sizeof(float), stream);
    gno_init_weights<<<dim3(41), dim3(256), 0, stream>>>(W1, b1, W2, b2, W3, b3, blob);
    gno_deg_kernel<<<dim3((En + 255) / 256), dim3(256), 0, stream>>>(neigh, deg);
    gno_edge_mfma<<<dim3(En / 64), dim3(256), 0, stream>>>(batch, points, neigh, blob, ksum);
    gno_out_kernel<<<dim3((Bn * Nn + 255) / 256), dim3(256), 0, stream>>>(
        batch, Wlin, ksum, deg, out);
}